// Round 5
// baseline (512.000 us; speedup 1.0000x reference)
//
#include <hip/hip_runtime.h>
#include <math.h>

#define BB 2048
#define MM 64

typedef __attribute__((ext_vector_type(8))) short short8;
typedef __attribute__((ext_vector_type(4))) float float4v;
typedef __attribute__((ext_vector_type(4))) int int4v;

union Frag { int4v v; short8 s; int u[4]; };

// workspace layout in 4-byte words:
#define OFF_A1    0        // w1 A-frags: [4 tr][4 ks][64 lane][4 u32] = 4096
#define OFF_A2    4096     // w2 A-frags: [4 tr][2 ks][64 lane][4 u32] = 2048
#define OFF_WAGGT 6144     // waggT [192][64] f32 = 12288
#define OFF_EP    18432    // e_parts [2][3][BB][64] f32 = 786432

__device__ __forceinline__ float sigmoidf_(float x) {
    return 1.0f / (1.0f + expf(-x));
}

__device__ __forceinline__ int pk2(float lo, float hi) {
    int r;
    asm("v_cvt_pk_bf16_f32 %0, %1, %2" : "=v"(r) : "v"(lo), "v"(hi));
    return r;
}

// pack w1/w2 into MFMA A-fragment layout; transpose wagg. (unchanged, verified)
__global__ __launch_bounds__(256) void prep_kernel(
    const float* __restrict__ w1, const float* __restrict__ w2,
    const float* __restrict__ wagg, int* __restrict__ wsI) {
    int t = blockIdx.x * 256 + threadIdx.x; // 0..12287
    if (t < 4096) {
        int r = t & 3, lane = (t >> 2) & 63, ks = (t >> 8) & 3, tr = t >> 10;
        int j = tr * 16 + (lane & 15);
        int k = ks * 32 + (lane >> 4) * 8 + 2 * r;
        wsI[OFF_A1 + t] = pk2(w1[j * 128 + k], w1[j * 128 + k + 1]);
    }
    if (t < 2048) {
        int r = t & 3, lane = (t >> 2) & 63, ks = (t >> 8) & 1, tr = t >> 9;
        int j = tr * 16 + (lane & 15);
        int k = ks * 32 + (lane >> 4) * 8 + 2 * r;
        wsI[OFF_A2 + t] = pk2(w2[j * 64 + k], w2[j * 64 + k + 1]);
    }
    if (t < 12288) {
        int k = t >> 6, j = t & 63;
        ((float*)wsI)[OFF_WAGGT + t] = wagg[j * 192 + k];
    }
}

// Fused: blocks [0,2048) = attn (one wave per (side,l,b), per-tc DNN for
// 64-VGPR fit); blocks [2048,3072) = hop-0 mean gather.
__global__ __launch_bounds__(256, 8) void fused_kernel(
    const float* __restrict__ ent_emb, const float* __restrict__ rec_emb,
    const float* __restrict__ rel_emb,
    const float* __restrict__ b1, const float* __restrict__ b2,
    const float* __restrict__ w3, const float* __restrict__ b3,
    const int* __restrict__ u_ent, const int* __restrict__ v_ent,
    const int* __restrict__ u_heads, const int* __restrict__ u_rels,
    const int* __restrict__ u_tails,
    const int* __restrict__ v_heads, const int* __restrict__ v_rels,
    const int* __restrict__ v_tails,
    const int* __restrict__ wsI, float* __restrict__ e_parts) {
    int lane = threadIdx.x & 63;
    int wv = threadIdx.x >> 6;

    if (blockIdx.x >= 2048) {
        // ---- hop-0 path ----
        int wt = (blockIdx.x - 2048) * 4 + wv; // 0..4095
        int b = wt & 2047;
        int side = wt >> 11;
        const int* ent = side ? v_ent : u_ent;
        const float* tab = side ? ent_emb : rec_emb;
        int em = ent[b * 64 + lane]; // per-lane index, broadcast via shfl
        float s0 = 0.f, s1 = 0.f, s2 = 0.f, s3 = 0.f;
        float s4 = 0.f, s5 = 0.f, s6 = 0.f, s7 = 0.f;
#pragma unroll
        for (int m = 0; m < 64; m += 8) {
            int e0 = __shfl(em, m + 0), e1 = __shfl(em, m + 1);
            int e2 = __shfl(em, m + 2), e3 = __shfl(em, m + 3);
            int e4 = __shfl(em, m + 4), e5 = __shfl(em, m + 5);
            int e6 = __shfl(em, m + 6), e7 = __shfl(em, m + 7);
            s0 += tab[(size_t)e0 * 64 + lane];
            s1 += tab[(size_t)e1 * 64 + lane];
            s2 += tab[(size_t)e2 * 64 + lane];
            s3 += tab[(size_t)e3 * 64 + lane];
            s4 += tab[(size_t)e4 * 64 + lane];
            s5 += tab[(size_t)e5 * 64 + lane];
            s6 += tab[(size_t)e6 * 64 + lane];
            s7 += tab[(size_t)e7 * 64 + lane];
        }
        float s = ((s0 + s1) + (s2 + s3)) + ((s4 + s5) + (s6 + s7));
        e_parts[((side * 3 + 0) * BB + b) * 64 + lane] = s * (1.0f / 64.0f);
        return;
    }

    // ---- attn path ----
    int wt = blockIdx.x * 4 + wv; // 0..8191
    int b = wt & 2047;
    int l = (wt >> 11) & 1;
    int side = wt >> 12;
    int c = lane & 15, g = lane >> 4;

    const int* heads = side ? v_heads : u_heads;
    const int* rels  = side ? v_rels  : u_rels;
    const int* tails = side ? v_tails : u_tails;
    int base = (l * BB + b) * MM + lane;
    int hidx = heads[base];
    int ridx = rels[base];
    int tidx = tails[base];

    const int4v* a1p = (const int4v*)(wsI + OFF_A1);
    const int4v* a2p = (const int4v*)(wsI + OFF_A2);
    float b3v = b3[0];

    // full DNN for one 16-neighbor column tile; math identical to the
    // verified round-4 kernel, just one tc at a time (VGPR <= 64).
    auto dnn_tc = [&](const int tc) -> float {
        int hn = __shfl(hidx, tc * 16 + c);
        int rn = __shfl(ridx, tc * 16 + c);
        const float4v* hp = (const float4v*)(ent_emb + (size_t)hn * 64 + g * 8);
        const float4v* rp = (const float4v*)(rel_emb + (size_t)rn * 64 + g * 8);
        float4v h0 = hp[0], h1 = hp[1], h2 = hp[8], h3 = hp[9];
        float4v r0 = rp[0], r1 = rp[1], r2 = rp[8], r3 = rp[9];
        Frag bx0, bx1, bx2, bx3;
        bx0.u[0] = pk2(h0[0], h0[1]); bx0.u[1] = pk2(h0[2], h0[3]);
        bx0.u[2] = pk2(h1[0], h1[1]); bx0.u[3] = pk2(h1[2], h1[3]);
        bx1.u[0] = pk2(h2[0], h2[1]); bx1.u[1] = pk2(h2[2], h2[3]);
        bx1.u[2] = pk2(h3[0], h3[1]); bx1.u[3] = pk2(h3[2], h3[3]);
        bx2.u[0] = pk2(r0[0], r0[1]); bx2.u[1] = pk2(r0[2], r0[3]);
        bx2.u[2] = pk2(r1[0], r1[1]); bx2.u[3] = pk2(r1[2], r1[3]);
        bx3.u[0] = pk2(r2[0], r2[1]); bx3.u[1] = pk2(r2[2], r2[3]);
        bx3.u[2] = pk2(r3[0], r3[1]); bx3.u[3] = pk2(r3[2], r3[3]);

        // layer 1
        float4v acc[4];
#pragma unroll
        for (int tr = 0; tr < 4; tr++) {
            float4v cacc = *(const float4v*)(b1 + tr * 16 + g * 4);
            Frag aA, aB, aC, aD;
            aA.v = a1p[(tr * 4 + 0) * 64 + lane];
            aB.v = a1p[(tr * 4 + 1) * 64 + lane];
            aC.v = a1p[(tr * 4 + 2) * 64 + lane];
            aD.v = a1p[(tr * 4 + 3) * 64 + lane];
            cacc = __builtin_amdgcn_mfma_f32_16x16x32_bf16(aA.s, bx0.s, cacc, 0, 0, 0);
            cacc = __builtin_amdgcn_mfma_f32_16x16x32_bf16(aB.s, bx1.s, cacc, 0, 0, 0);
            cacc = __builtin_amdgcn_mfma_f32_16x16x32_bf16(aC.s, bx2.s, cacc, 0, 0, 0);
            cacc = __builtin_amdgcn_mfma_f32_16x16x32_bf16(aD.s, bx3.s, cacc, 0, 0, 0);
            acc[tr] = cacc;
        }

        // relu + pack + re-layout C-frag -> B-frag (verified mapping)
        int pk[4][2];
#pragma unroll
        for (int trp = 0; trp < 4; trp++) {
#pragma unroll
            for (int ip = 0; ip < 2; ip++) {
                float lo = fmaxf(acc[trp][2 * ip], 0.0f);
                float hi = fmaxf(acc[trp][2 * ip + 1], 0.0f);
                pk[trp][ip] = pk2(lo, hi);
            }
        }
        Frag b2f[2];
#pragma unroll
        for (int ks2 = 0; ks2 < 2; ks2++) {
#pragma unroll
            for (int r = 0; r < 4; r++) {
                int srclane = (lane & 15) | ((lane & 16) << 1) | ((r >> 1) << 4);
                int va = __shfl(pk[2 * ks2 + 0][r & 1], srclane);
                int vb = __shfl(pk[2 * ks2 + 1][r & 1], srclane);
                b2f[ks2].u[r] = (lane & 32) ? vb : va;
            }
        }

        // layer 2
        float4v ac2[4];
#pragma unroll
        for (int tr = 0; tr < 4; tr++) {
            float4v cacc = *(const float4v*)(b2 + tr * 16 + g * 4);
            Frag aA, aB;
            aA.v = a2p[(tr * 2 + 0) * 64 + lane];
            aB.v = a2p[(tr * 2 + 1) * 64 + lane];
            cacc = __builtin_amdgcn_mfma_f32_16x16x32_bf16(aA.s, b2f[0].s, cacc, 0, 0, 0);
            cacc = __builtin_amdgcn_mfma_f32_16x16x32_bf16(aB.s, b2f[1].s, cacc, 0, 0, 0);
            ac2[tr] = cacc;
        }

        // layer 3 + reduce over g
        float pt = 0.0f;
#pragma unroll
        for (int tr = 0; tr < 4; tr++) {
            float4v w3t = *(const float4v*)(w3 + tr * 16 + g * 4);
#pragma unroll
            for (int i = 0; i < 4; i++)
                pt = fmaf(fmaxf(ac2[tr][i], 0.0f), w3t[i], pt);
        }
        pt += __shfl_xor(pt, 16);
        pt += __shfl_xor(pt, 32);
        return sigmoidf_(pt + b3v);
    };

    float pv0 = dnn_tc(0);
    float pv1 = dnn_tc(1);
    float pv2 = dnn_tc(2);
    float pv3 = dnn_tc(3);

    // softmax over 64 m (values replicated over g)
    float mx = fmaxf(fmaxf(pv0, pv1), fmaxf(pv2, pv3));
#pragma unroll
    for (int o = 1; o < 16; o <<= 1) mx = fmaxf(mx, __shfl_xor(mx, o));
    float e0 = expf(pv0 - mx), e1 = expf(pv1 - mx);
    float e2 = expf(pv2 - mx), e3 = expf(pv3 - mx);
    float sm = (e0 + e1) + (e2 + e3);
#pragma unroll
    for (int o = 1; o < 16; o <<= 1) sm += __shfl_xor(sm, o);
    float inv = 1.0f / sm;
    float pA[4] = {e0 * inv, e1 * inv, e2 * inv, e3 * inv}; // static-indexed only

    // PV gather: 8 outstanding loads per batch
    float aa0 = 0.f, aa1 = 0.f, aa2 = 0.f, aa3 = 0.f;
    float aa4 = 0.f, aa5 = 0.f, aa6 = 0.f, aa7 = 0.f;
#pragma unroll
    for (int m = 0; m < 64; m += 8) {
        float pm0 = __shfl(pA[(m + 0) >> 4], (m + 0) & 15);
        float pm1 = __shfl(pA[(m + 1) >> 4], (m + 1) & 15);
        float pm2 = __shfl(pA[(m + 2) >> 4], (m + 2) & 15);
        float pm3 = __shfl(pA[(m + 3) >> 4], (m + 3) & 15);
        float pm4 = __shfl(pA[(m + 4) >> 4], (m + 4) & 15);
        float pm5 = __shfl(pA[(m + 5) >> 4], (m + 5) & 15);
        float pm6 = __shfl(pA[(m + 6) >> 4], (m + 6) & 15);
        float pm7 = __shfl(pA[(m + 7) >> 4], (m + 7) & 15);
        int tm0 = __shfl(tidx, m + 0), tm1 = __shfl(tidx, m + 1);
        int tm2 = __shfl(tidx, m + 2), tm3 = __shfl(tidx, m + 3);
        int tm4 = __shfl(tidx, m + 4), tm5 = __shfl(tidx, m + 5);
        int tm6 = __shfl(tidx, m + 6), tm7 = __shfl(tidx, m + 7);
        aa0 = fmaf(pm0, ent_emb[(size_t)tm0 * 64 + lane], aa0);
        aa1 = fmaf(pm1, ent_emb[(size_t)tm1 * 64 + lane], aa1);
        aa2 = fmaf(pm2, ent_emb[(size_t)tm2 * 64 + lane], aa2);
        aa3 = fmaf(pm3, ent_emb[(size_t)tm3 * 64 + lane], aa3);
        aa4 = fmaf(pm4, ent_emb[(size_t)tm4 * 64 + lane], aa4);
        aa5 = fmaf(pm5, ent_emb[(size_t)tm5 * 64 + lane], aa5);
        aa6 = fmaf(pm6, ent_emb[(size_t)tm6 * 64 + lane], aa6);
        aa7 = fmaf(pm7, ent_emb[(size_t)tm7 * 64 + lane], aa7);
    }
    float s = ((aa0 + aa1) + (aa2 + aa3)) + ((aa4 + aa5) + (aa6 + aa7));
    e_parts[((side * 3 + (l + 1)) * BB + b) * 64 + lane] = s;
}

// final: per b, user/item agg MLP + dot + sigmoid (unchanged, verified)
__global__ __launch_bounds__(256) void final_kernel(
    const float* __restrict__ bagg, const float* __restrict__ wsF,
    float* __restrict__ out) {
    const float* waggT = wsF + OFF_WAGGT;
    const float* ep = wsF + OFF_EP;
    int b = blockIdx.x * 4 + (threadIdx.x >> 6);
    int lane = threadIdx.x & 63;
    float eu[3], ev[3];
#pragma unroll
    for (int cc = 0; cc < 3; cc++) {
        eu[cc] = ep[((0 * 3 + cc) * BB + b) * 64 + lane];
        ev[cc] = ep[((1 * 3 + cc) * BB + b) * 64 + lane];
    }
    float us = bagg[lane], it = bagg[lane];
#pragma unroll
    for (int k = 0; k < 192; k++) {
        float w = waggT[k * 64 + lane];
        us = fmaf(__shfl(eu[k >> 6], k & 63), w, us);
        it = fmaf(__shfl(ev[k >> 6], k & 63), w, it);
    }
    us = sigmoidf_(us);
    it = sigmoidf_(it);
    float prod = us * it;
#pragma unroll
    for (int o = 32; o > 0; o >>= 1) prod += __shfl_xor(prod, o);
    if (lane == 0) out[b] = sigmoidf_(prod);
}

extern "C" void kernel_launch(void* const* d_in, const int* in_sizes, int n_in,
                              void* d_out, int out_size, void* d_ws, size_t ws_size,
                              hipStream_t stream) {
    const float* ent_emb = (const float*)d_in[0];
    const float* rec_emb = (const float*)d_in[1];
    const float* rel_emb = (const float*)d_in[2];
    const float* w1   = (const float*)d_in[3];
    const float* b1   = (const float*)d_in[4];
    const float* w2   = (const float*)d_in[5];
    const float* b2   = (const float*)d_in[6];
    const float* w3   = (const float*)d_in[7];
    const float* b3   = (const float*)d_in[8];
    const float* wagg = (const float*)d_in[9];
    const float* bagg = (const float*)d_in[10];
    const int* u_ent   = (const int*)d_in[11];
    const int* u_heads = (const int*)d_in[12];
    const int* u_rels  = (const int*)d_in[13];
    const int* u_tails = (const int*)d_in[14];
    const int* v_ent   = (const int*)d_in[15];
    const int* v_heads = (const int*)d_in[16];
    const int* v_rels  = (const int*)d_in[17];
    const int* v_tails = (const int*)d_in[18];

    int* wsI = (int*)d_ws;
    float* wsF = (float*)d_ws;
    float* e_parts = wsF + OFF_EP;
    float* out = (float*)d_out;

    prep_kernel<<<48, 256, 0, stream>>>(w1, w2, wagg, wsI);
    fused_kernel<<<3072, 256, 0, stream>>>(ent_emb, rec_emb, rel_emb,
                                           b1, b2, w3, b3,
                                           u_ent, v_ent,
                                           u_heads, u_rels, u_tails,
                                           v_heads, v_rels, v_tails,
                                           wsI, e_parts);
    final_kernel<<<512, 256, 0, stream>>>(bagg, wsF, out);
}

// Round 6
// 364.707 us; speedup vs baseline: 1.4039x; 1.4039x over previous
//
#include <hip/hip_runtime.h>
#include <math.h>

#define BB 2048
#define MM 64

typedef __attribute__((ext_vector_type(8))) short short8;
typedef __attribute__((ext_vector_type(4))) float float4v;
typedef __attribute__((ext_vector_type(4))) int int4v;

union Frag { int4v v; short8 s; int u[4]; };

// workspace layout in 4-byte words:
#define OFF_A1    0        // w1 A-frags: [4 tr][4 ks][64 lane][4 u32] = 4096
#define OFF_A2    4096     // w2 A-frags: [4 tr][2 ks][64 lane][4 u32] = 2048
#define OFF_WAGGT 6144     // waggT [192][64] f32 = 12288
#define OFF_EP    18432    // e_parts [2][3][BB][64] f32 = 786432

__device__ __forceinline__ float sigmoidf_(float x) {
    return 1.0f / (1.0f + expf(-x));
}

__device__ __forceinline__ int pk2(float lo, float hi) {
    int r;
    asm("v_cvt_pk_bf16_f32 %0, %1, %2" : "=v"(r) : "v"(lo), "v"(hi));
    return r;
}

// pack w1/w2 into MFMA A-fragment layout; transpose wagg. (verified)
__global__ __launch_bounds__(256) void prep_kernel(
    const float* __restrict__ w1, const float* __restrict__ w2,
    const float* __restrict__ wagg, int* __restrict__ wsI) {
    int t = blockIdx.x * 256 + threadIdx.x; // 0..12287
    if (t < 4096) {
        int r = t & 3, lane = (t >> 2) & 63, ks = (t >> 8) & 3, tr = t >> 10;
        int j = tr * 16 + (lane & 15);
        int k = ks * 32 + (lane >> 4) * 8 + 2 * r;
        wsI[OFF_A1 + t] = pk2(w1[j * 128 + k], w1[j * 128 + k + 1]);
    }
    if (t < 2048) {
        int r = t & 3, lane = (t >> 2) & 63, ks = (t >> 8) & 1, tr = t >> 9;
        int j = tr * 16 + (lane & 15);
        int k = ks * 32 + (lane >> 4) * 8 + 2 * r;
        wsI[OFF_A2 + t] = pk2(w2[j * 64 + k], w2[j * 64 + k + 1]);
    }
    if (t < 12288) {
        int k = t >> 6, j = t & 63;
        ((float*)wsI)[OFF_WAGGT + t] = wagg[j * 192 + k];
    }
}

// Fused: blocks [0,2048) = attn (round-4 verified body, natural VGPR);
// blocks [2048,3072) = hop-0 mean gather. NO min-waves launch bound —
// round-5 showed forcing 8 waves/EU spills ~900 MB of scratch.
__global__ __launch_bounds__(256) void fused_kernel(
    const float* __restrict__ ent_emb, const float* __restrict__ rec_emb,
    const float* __restrict__ rel_emb,
    const float* __restrict__ b1, const float* __restrict__ b2,
    const float* __restrict__ w3, const float* __restrict__ b3,
    const int* __restrict__ u_ent, const int* __restrict__ v_ent,
    const int* __restrict__ u_heads, const int* __restrict__ u_rels,
    const int* __restrict__ u_tails,
    const int* __restrict__ v_heads, const int* __restrict__ v_rels,
    const int* __restrict__ v_tails,
    const int* __restrict__ wsI, float* __restrict__ e_parts) {
    int lane = threadIdx.x & 63;
    int wv = threadIdx.x >> 6;

    if (blockIdx.x >= 2048) {
        // ---- hop-0 path ----
        int wt = (blockIdx.x - 2048) * 4 + wv; // 0..4095
        int b = wt & 2047;
        int side = wt >> 11;
        const int* ent = side ? v_ent : u_ent;
        const float* tab = side ? ent_emb : rec_emb;
        int em = ent[b * 64 + lane];
        float s0 = 0.f, s1 = 0.f, s2 = 0.f, s3 = 0.f;
        float s4 = 0.f, s5 = 0.f, s6 = 0.f, s7 = 0.f;
#pragma unroll
        for (int m = 0; m < 64; m += 8) {
            int e0 = __shfl(em, m + 0), e1 = __shfl(em, m + 1);
            int e2 = __shfl(em, m + 2), e3 = __shfl(em, m + 3);
            int e4 = __shfl(em, m + 4), e5 = __shfl(em, m + 5);
            int e6 = __shfl(em, m + 6), e7 = __shfl(em, m + 7);
            s0 += tab[(size_t)e0 * 64 + lane];
            s1 += tab[(size_t)e1 * 64 + lane];
            s2 += tab[(size_t)e2 * 64 + lane];
            s3 += tab[(size_t)e3 * 64 + lane];
            s4 += tab[(size_t)e4 * 64 + lane];
            s5 += tab[(size_t)e5 * 64 + lane];
            s6 += tab[(size_t)e6 * 64 + lane];
            s7 += tab[(size_t)e7 * 64 + lane];
        }
        float s = ((s0 + s1) + (s2 + s3)) + ((s4 + s5) + (s6 + s7));
        e_parts[((side * 3 + 0) * BB + b) * 64 + lane] = s * (1.0f / 64.0f);
        return;
    }

    // ---- attn path (round-4 verified body) ----
    int wt = blockIdx.x * 4 + wv; // 0..8191
    int b = wt & 2047;
    int l = (wt >> 11) & 1;
    int side = wt >> 12;
    int c = lane & 15, g = lane >> 4;

    const int* heads = side ? v_heads : u_heads;
    const int* rels  = side ? v_rels  : u_rels;
    const int* tails = side ? v_tails : u_tails;
    int base = (l * BB + b) * MM + lane;
    int hidx = heads[base];
    int ridx = rels[base];
    int tidx = tails[base];

    const int4v* a1p = (const int4v*)(wsI + OFF_A1);
    const int4v* a2p = (const int4v*)(wsI + OFF_A2);

    // ---- B fragments of X^T: lane holds col m = tc*16+c, k = g*8+e ----
    Frag bx[4][4];
#pragma unroll
    for (int tc = 0; tc < 4; tc++) {
        int hn = __shfl(hidx, tc * 16 + c);
        int rn = __shfl(ridx, tc * 16 + c);
        const float4v* hp = (const float4v*)(ent_emb + (size_t)hn * 64 + g * 8);
        const float4v* rp = (const float4v*)(rel_emb + (size_t)rn * 64 + g * 8);
        float4v h0 = hp[0], h1 = hp[1], h2 = hp[8], h3 = hp[9];
        float4v r0 = rp[0], r1 = rp[1], r2 = rp[8], r3 = rp[9];
        bx[tc][0].u[0] = pk2(h0[0], h0[1]); bx[tc][0].u[1] = pk2(h0[2], h0[3]);
        bx[tc][0].u[2] = pk2(h1[0], h1[1]); bx[tc][0].u[3] = pk2(h1[2], h1[3]);
        bx[tc][1].u[0] = pk2(h2[0], h2[1]); bx[tc][1].u[1] = pk2(h2[2], h2[3]);
        bx[tc][1].u[2] = pk2(h3[0], h3[1]); bx[tc][1].u[3] = pk2(h3[2], h3[3]);
        bx[tc][2].u[0] = pk2(r0[0], r0[1]); bx[tc][2].u[1] = pk2(r0[2], r0[3]);
        bx[tc][2].u[2] = pk2(r1[0], r1[1]); bx[tc][2].u[3] = pk2(r1[2], r1[3]);
        bx[tc][3].u[0] = pk2(r2[0], r2[1]); bx[tc][3].u[1] = pk2(r2[2], r2[3]);
        bx[tc][3].u[2] = pk2(r3[0], r3[1]); bx[tc][3].u[3] = pk2(r3[2], r3[3]);
    }

    // ---- layer 1 ----
    float4v acc[4][4];
#pragma unroll
    for (int tr = 0; tr < 4; tr++) {
        float4v bias = *(const float4v*)(b1 + tr * 16 + g * 4);
        Frag a1s[4];
#pragma unroll
        for (int ks = 0; ks < 4; ks++)
            a1s[ks].v = a1p[(tr * 4 + ks) * 64 + lane];
#pragma unroll
        for (int tc = 0; tc < 4; tc++) {
            float4v cacc = bias;
#pragma unroll
            for (int ks = 0; ks < 4; ks++)
                cacc = __builtin_amdgcn_mfma_f32_16x16x32_bf16(
                    a1s[ks].s, bx[tc][ks].s, cacc, 0, 0, 0);
            acc[tr][tc] = cacc;
        }
    }

    // ---- relu + re-layout C-frag -> B-frag (verified mapping) ----
    Frag b2f[4][2];
#pragma unroll
    for (int tc = 0; tc < 4; tc++) {
        int pk[4][2];
#pragma unroll
        for (int trp = 0; trp < 4; trp++) {
#pragma unroll
            for (int ip = 0; ip < 2; ip++) {
                float lo = fmaxf(acc[trp][tc][2 * ip], 0.0f);
                float hi = fmaxf(acc[trp][tc][2 * ip + 1], 0.0f);
                pk[trp][ip] = pk2(lo, hi);
            }
        }
#pragma unroll
        for (int ks2 = 0; ks2 < 2; ks2++) {
#pragma unroll
            for (int r = 0; r < 4; r++) {
                int srclane = (lane & 15) | ((lane & 16) << 1) | ((r >> 1) << 4);
                int va = __shfl(pk[2 * ks2 + 0][r & 1], srclane);
                int vb = __shfl(pk[2 * ks2 + 1][r & 1], srclane);
                b2f[tc][ks2].u[r] = (lane & 32) ? vb : va;
            }
        }
    }

    // ---- layer 2 ----
    float4v acc2[4][4];
#pragma unroll
    for (int tr = 0; tr < 4; tr++) {
        float4v bias = *(const float4v*)(b2 + tr * 16 + g * 4);
        Frag a2s[2];
#pragma unroll
        for (int ks = 0; ks < 2; ks++)
            a2s[ks].v = a2p[(tr * 2 + ks) * 64 + lane];
#pragma unroll
        for (int tc = 0; tc < 4; tc++) {
            float4v cacc = bias;
#pragma unroll
            for (int ks = 0; ks < 2; ks++)
                cacc = __builtin_amdgcn_mfma_f32_16x16x32_bf16(
                    a2s[ks].s, b2f[tc][ks].s, cacc, 0, 0, 0);
            acc2[tr][tc] = cacc;
        }
    }

    // ---- layer 3 + sigmoid ----
    float4v w3f[4];
#pragma unroll
    for (int tr = 0; tr < 4; tr++)
        w3f[tr] = *(const float4v*)(w3 + tr * 16 + g * 4);
    float b3v = b3[0];

    float pv[4];
#pragma unroll
    for (int tc = 0; tc < 4; tc++) {
        float pt = 0.0f;
#pragma unroll
        for (int tr = 0; tr < 4; tr++) {
#pragma unroll
            for (int i = 0; i < 4; i++)
                pt = fmaf(fmaxf(acc2[tr][tc][i], 0.0f), w3f[tr][i], pt);
        }
        pt += __shfl_xor(pt, 16);
        pt += __shfl_xor(pt, 32);
        pv[tc] = sigmoidf_(pt + b3v);
    }

    // ---- softmax over all 64 m ----
    float mx = fmaxf(fmaxf(pv[0], pv[1]), fmaxf(pv[2], pv[3]));
#pragma unroll
    for (int o = 1; o < 16; o <<= 1) mx = fmaxf(mx, __shfl_xor(mx, o));
    float ex[4];
    float sm = 0.0f;
#pragma unroll
    for (int tc = 0; tc < 4; tc++) { ex[tc] = expf(pv[tc] - mx); sm += ex[tc]; }
#pragma unroll
    for (int o = 1; o < 16; o <<= 1) sm += __shfl_xor(sm, o);
    float inv = 1.0f / sm;
    float p[4];
#pragma unroll
    for (int tc = 0; tc < 4; tc++) p[tc] = ex[tc] * inv;

    // ---- PV gather: 16 outstanding coalesced 256B loads per batch ----
    float aa[16];
#pragma unroll
    for (int i = 0; i < 16; i++) aa[i] = 0.0f;
#pragma unroll
    for (int m = 0; m < 64; m += 16) {
        float pm[16];
        int tm[16];
#pragma unroll
        for (int i = 0; i < 16; i++) {
            pm[i] = __shfl(p[(m + i) >> 4], (m + i) & 15);
            tm[i] = __shfl(tidx, m + i);
        }
#pragma unroll
        for (int i = 0; i < 16; i++)
            aa[i] = fmaf(pm[i], ent_emb[(size_t)tm[i] * 64 + lane], aa[i]);
    }
    float s = 0.0f;
#pragma unroll
    for (int i = 0; i < 16; i++) s += aa[i];
    e_parts[((side * 3 + (l + 1)) * BB + b) * 64 + lane] = s;
}

// final: per b, user/item agg MLP + dot + sigmoid (verified)
__global__ __launch_bounds__(256) void final_kernel(
    const float* __restrict__ bagg, const float* __restrict__ wsF,
    float* __restrict__ out) {
    const float* waggT = wsF + OFF_WAGGT;
    const float* ep = wsF + OFF_EP;
    int b = blockIdx.x * 4 + (threadIdx.x >> 6);
    int lane = threadIdx.x & 63;
    float eu[3], ev[3];
#pragma unroll
    for (int cc = 0; cc < 3; cc++) {
        eu[cc] = ep[((0 * 3 + cc) * BB + b) * 64 + lane];
        ev[cc] = ep[((1 * 3 + cc) * BB + b) * 64 + lane];
    }
    float us = bagg[lane], it = bagg[lane];
#pragma unroll
    for (int k = 0; k < 192; k++) {
        float w = waggT[k * 64 + lane];
        us = fmaf(__shfl(eu[k >> 6], k & 63), w, us);
        it = fmaf(__shfl(ev[k >> 6], k & 63), w, it);
    }
    us = sigmoidf_(us);
    it = sigmoidf_(it);
    float prod = us * it;
#pragma unroll
    for (int o = 32; o > 0; o >>= 1) prod += __shfl_xor(prod, o);
    if (lane == 0) out[b] = sigmoidf_(prod);
}

extern "C" void kernel_launch(void* const* d_in, const int* in_sizes, int n_in,
                              void* d_out, int out_size, void* d_ws, size_t ws_size,
                              hipStream_t stream) {
    const float* ent_emb = (const float*)d_in[0];
    const float* rec_emb = (const float*)d_in[1];
    const float* rel_emb = (const float*)d_in[2];
    const float* w1   = (const float*)d_in[3];
    const float* b1   = (const float*)d_in[4];
    const float* w2   = (const float*)d_in[5];
    const float* b2   = (const float*)d_in[6];
    const float* w3   = (const float*)d_in[7];
    const float* b3   = (const float*)d_in[8];
    const float* wagg = (const float*)d_in[9];
    const float* bagg = (const float*)d_in[10];
    const int* u_ent   = (const int*)d_in[11];
    const int* u_heads = (const int*)d_in[12];
    const int* u_rels  = (const int*)d_in[13];
    const int* u_tails = (const int*)d_in[14];
    const int* v_ent   = (const int*)d_in[15];
    const int* v_heads = (const int*)d_in[16];
    const int* v_rels  = (const int*)d_in[17];
    const int* v_tails = (const int*)d_in[18];

    int* wsI = (int*)d_ws;
    float* wsF = (float*)d_ws;
    float* e_parts = wsF + OFF_EP;
    float* out = (float*)d_out;

    prep_kernel<<<48, 256, 0, stream>>>(w1, w2, wagg, wsI);
    fused_kernel<<<3072, 256, 0, stream>>>(ent_emb, rec_emb, rel_emb,
                                           b1, b2, w3, b3,
                                           u_ent, v_ent,
                                           u_heads, u_rels, u_tails,
                                           v_heads, v_rels, v_tails,
                                           wsI, e_parts);
    final_kernel<<<512, 256, 0, stream>>>(bagg, wsF, out);
}